// Round 7
// baseline (66.472 us; speedup 1.0000x reference)
//
#include <hip/hip_runtime.h>
#include <math.h>

typedef __attribute__((ext_vector_type(8))) short bf16x8;
typedef __attribute__((ext_vector_type(4))) float f32x4;
typedef __attribute__((ext_vector_type(4))) unsigned int u32x4;

#define B_ 4
#define L_ 2048
#define S_ 2048
#define H_ 8
#define E_ 64
#define D_ 64
#define NT_ 32                      // kv tiles of 64 per (b,h)
#define TILE_BYTES 16384            // 8KB K image + 8KB V^T image
#define WS_NEEDED ((size_t)B_ * H_ * NT_ * TILE_BYTES)
#define SCL (0.125f * 1.44269504088896f)   // 1/sqrt(E) * log2(e)

__device__ __forceinline__ unsigned short f2bf(float x) {
    unsigned int u = __builtin_bit_cast(unsigned int, x);
    u += 0x7fffu + ((u >> 16) & 1u);
    return (unsigned short)(u >> 16);
}
// kv-row permute so S^T C-fragment layout == PV A-operand layout (verified rounds 1-5)
__device__ __forceinline__ int rho(int r) {
    return (r & 32) | (((r >> 2) & 1) << 4) | (((r >> 3) & 3) << 2) | (r & 3);
}

// ---------------- prep: K -> bf16 tile image (rho + XOR swizzle), V -> V^T bf16 image ----------------
__global__ __launch_bounds__(256) void prep_kv(const float* __restrict__ K,
                                               const float* __restrict__ V,
                                               unsigned short* __restrict__ ws)
{
    __shared__ __align__(16) unsigned short vt[64][80];
    const int tid = threadIdx.x;
    const int bid = blockIdx.x;         // bh*NT_ + kt
    const int kt = bid & (NT_ - 1);
    const int bh = bid >> 5;
    const int b  = bh >> 3, h = bh & 7;
    const int s0 = kt * 64;
    const int r  = tid >> 2;
    const int e0 = (tid & 3) * 16;

    const float* krow = K + (((size_t)(b * S_ + s0 + r)) * H_ + h) * E_ + e0;
    const float* vrow = V + (((size_t)(b * S_ + s0 + r)) * H_ + h) * D_ + e0;
    char* tile = (char*)(ws) + ((size_t)bid * TILE_BYTES);

    unsigned short kb[16];
    #pragma unroll
    for (int i = 0; i < 4; ++i) {
        f32x4 k4 = *(const f32x4*)(krow + i * 4);
        #pragma unroll
        for (int jq = 0; jq < 4; ++jq) kb[i * 4 + jq] = f2bf(k4[jq]);
    }
    {
        const int rr = rho(r);
        const int m  = (rr & 7) << 4;
        char* kbase = tile + rr * 128;
        u32x4 lo, hi;
        #pragma unroll
        for (int jq = 0; jq < 4; ++jq) {
            lo[jq] = (unsigned)kb[2 * jq] | ((unsigned)kb[2 * jq + 1] << 16);
            hi[jq] = (unsigned)kb[8 + 2 * jq] | ((unsigned)kb[9 + 2 * jq] << 16);
        }
        *(u32x4*)(kbase + ((2 * e0) ^ m))      = lo;
        *(u32x4*)(kbase + ((2 * e0 + 16) ^ m)) = hi;
    }
    #pragma unroll
    for (int i = 0; i < 4; ++i) {
        f32x4 v4 = *(const f32x4*)(vrow + i * 4);
        #pragma unroll
        for (int jq = 0; jq < 4; ++jq) vt[e0 + i * 4 + jq][r] = f2bf(v4[jq]);
    }
    __syncthreads();
    {
        const int d  = tid >> 2;
        const int c0 = (tid & 3) * 16;
        const int m  = (d & 7) << 4;
        char* vbase = tile + 8192 + d * 128;
        u32x4 lo = *(const u32x4*)&vt[d][c0];
        u32x4 hi = *(const u32x4*)&vt[d][c0 + 8];
        *(u32x4*)(vbase + ((2 * c0) ^ m))      = lo;
        *(u32x4*)(vbase + ((2 * c0 + 16) ^ m)) = hi;
    }
}

// ---------------- attention: split-K pairs via self-contained ranges, LDS combine ----------------
#define GL16(dst, p, o) asm volatile("global_load_dwordx4 %0, %1, off offset:" o \
                                     : "=&v"(dst) : "v"(p) : "memory")

#define ISSUE_K() do { \
    GL16(ka[0], pKa, "-3072"); GL16(ka[1], pKb, "-3072"); \
    GL16(ka[2], pKa, "-1024"); GL16(ka[3], pKb, "-1024"); \
    GL16(ka[4], pKa, "1024");  GL16(ka[5], pKb, "1024");  \
    GL16(ka[6], pKa, "3072");  GL16(ka[7], pKb, "3072"); } while (0)

#define ISSUE_V() do { \
    GL16(vb[0], pVa, "-3072"); GL16(vb[1], pVb, "-3072"); \
    GL16(vb[2], pVa, "-1024"); GL16(vb[3], pVb, "-1024"); \
    GL16(vb[4], pVa, "1024");  GL16(vb[5], pVb, "1024");  \
    GL16(vb[6], pVa, "3072");  GL16(vb[7], pVb, "3072"); } while (0)

// one contiguous kv-range [kv_from, kv_to) for 32-row q-tile qt; partials into LDS slot
__device__ __forceinline__ void do_range(
    const float* __restrict__ Q, const char* __restrict__ tb,
    int b0, int h, int qt, int kv_from, int kv_to, int diag_kt,
    int lq, int g, float (*LaccS)[66], float* LlS)
{
    if (kv_from >= kv_to) return;
    int qrow[2];
    qrow[0] = qt * 32 + lq;
    qrow[1] = qt * 32 + 16 + lq;

    // Q fragments (B-operand), scale*log2e folded => scores in exp2 domain
    bf16x8 qf[2][2];
    #pragma unroll
    for (int qs = 0; qs < 2; ++qs) {
        const float* qptr = Q + (((size_t)(b0 * L_ + qrow[qs])) * H_ + h) * E_;
        #pragma unroll
        for (int eb = 0; eb < 2; ++eb) {
            const float* pq = qptr + eb * 32 + g * 8;
            f32x4 a = *(const f32x4*)pq;
            f32x4 b = *(const f32x4*)(pq + 4);
            bf16x8 qv;
            #pragma unroll
            for (int k = 0; k < 4; ++k) {
                qv[k]     = (short)f2bf(a[k] * SCL);
                qv[4 + k] = (short)f2bf(b[k] * SCL);
            }
            qf[qs][eb] = qv;
        }
    }

    // per-lane pre-swizzled pointers (+3072 centers the ±3072 literal offsets)
    const int mm  = (lq & 7) << 4;
    const char* pKa = tb + (size_t)kv_from * TILE_BYTES + lq * 128 + ((16 * g) ^ mm) + 3072;
    const char* pKb = tb + (size_t)kv_from * TILE_BYTES + lq * 128 + (((64 + 16 * g)) ^ mm) + 3072;
    const char* pVa = pKa + 8192;
    const char* pVb = pKb + 8192;

    u32x4 ka[8], vb[8];
    f32x4 acc[2][4] = {};
    float ls[2] = {0.f, 0.f};

    ISSUE_K();
    ISSUE_V();

    for (int kt = kv_from; kt < kv_to; ++kt) {
        // ---- wait K(kt) (V(kt) still in flight) ----
        asm volatile("s_waitcnt vmcnt(8)" ::: "memory");
        __builtin_amdgcn_sched_barrier(0);

        // ---- QK^T (swapped) from registers ----
        f32x4 sc[2][4];
        __builtin_amdgcn_s_setprio(1);
        #pragma unroll
        for (int st = 0; st < 4; ++st) {
            bf16x8 k0 = __builtin_bit_cast(bf16x8, ka[2 * st]);
            bf16x8 k1 = __builtin_bit_cast(bf16x8, ka[2 * st + 1]);
            #pragma unroll
            for (int qs = 0; qs < 2; ++qs) {
                f32x4 z = {0.f, 0.f, 0.f, 0.f};
                f32x4 cc = __builtin_amdgcn_mfma_f32_16x16x32_bf16(k0, qf[qs][0], z, 0, 0, 0);
                sc[qs][st] = __builtin_amdgcn_mfma_f32_16x16x32_bf16(k1, qf[qs][1], cc, 0, 0, 0);
            }
        }
        __builtin_amdgcn_s_setprio(0);

        const bool hasnext = (kt + 1 < kv_to);
        if (hasnext) { pKa += TILE_BYTES; pKb += TILE_BYTES; ISSUE_K(); }

        // ---- softmax (fixed base, exp2 domain) + pack P ----
        const int kv0 = kt * 64;
        u32x4 pw[2][2];
        #pragma unroll
        for (int qs = 0; qs < 2; ++qs) {
            #pragma unroll
            for (int st = 0; st < 4; ++st) {
                f32x4 cc = sc[qs][st];
                if (kt == diag_kt) {   // diagonal tile: causal mask
                    #pragma unroll
                    for (int r = 0; r < 4; ++r) {
                        const int kv = kv0 + 32 * (st >> 1) + 8 * g + 4 * (st & 1) + r;
                        if (kv > qrow[qs]) cc[r] = -INFINITY;
                    }
                }
                f32x4 ev;
                #pragma unroll
                for (int r = 0; r < 4; ++r)
                    asm("v_exp_f32 %0, %1" : "=v"(ev[r]) : "v"(cc[r]));
                ls[qs] += (ev[0] + ev[1]) + (ev[2] + ev[3]);
                asm("v_cvt_pk_bf16_f32 %0, %1, %2" : "=v"(pw[qs][st >> 1][2 * (st & 1)])     : "v"(ev[0]), "v"(ev[1]));
                asm("v_cvt_pk_bf16_f32 %0, %1, %2" : "=v"(pw[qs][st >> 1][2 * (st & 1) + 1]) : "v"(ev[2]), "v"(ev[3]));
            }
        }

        // ---- wait V(kt) ----
        if (hasnext) asm volatile("s_waitcnt vmcnt(8)" ::: "memory");
        else         asm volatile("s_waitcnt vmcnt(0)" ::: "memory");
        __builtin_amdgcn_sched_barrier(0);

        // ---- PV: O^T += V^T . P^T ----
        __builtin_amdgcn_s_setprio(1);
        #pragma unroll
        for (int dt = 0; dt < 4; ++dt) {
            bf16x8 v0 = __builtin_bit_cast(bf16x8, vb[2 * dt]);
            bf16x8 v1 = __builtin_bit_cast(bf16x8, vb[2 * dt + 1]);
            #pragma unroll
            for (int qs = 0; qs < 2; ++qs) {
                acc[qs][dt] = __builtin_amdgcn_mfma_f32_16x16x32_bf16(v0, __builtin_bit_cast(bf16x8, pw[qs][0]), acc[qs][dt], 0, 0, 0);
                acc[qs][dt] = __builtin_amdgcn_mfma_f32_16x16x32_bf16(v1, __builtin_bit_cast(bf16x8, pw[qs][1]), acc[qs][dt], 0, 0, 0);
            }
        }
        __builtin_amdgcn_s_setprio(0);

        if (hasnext) { pVa += TILE_BYTES; pVb += TILE_BYTES; ISSUE_V(); }
    }

    // ---- flush partials into the combine slot ----
    #pragma unroll
    for (int qs = 0; qs < 2; ++qs) {
        #pragma unroll
        for (int dt = 0; dt < 4; ++dt)
            #pragma unroll
            for (int r = 0; r < 4; ++r)
                atomicAdd(&LaccS[qs * 16 + lq][dt * 16 + 4 * g + r], acc[qs][dt][r]);
        atomicAdd(&LlS[qs * 16 + lq], ls[qs]);
    }
}

__global__ __launch_bounds__(256, 2) void attn7(const float* __restrict__ Q,
                                                const unsigned short* __restrict__ ws,
                                                float* __restrict__ O)
{
    __shared__ float Lacc[4][32][66];   // [pair*2+side][row][d]  (+2 pad)
    __shared__ float Ll[4][32];

    const int tid  = threadIdx.x;
    const int lane = tid & 63;
    const int w    = tid >> 6;        // wave 0..3
    const int lq   = lane & 15;
    const int g    = lane >> 4;

    const int bid = blockIdx.x;
    const int bh  = bid & 31;         // bh pinned to XCD (bid%8 == bh%8)
    const int j   = bid >> 5;         // 0..15
    const int b0  = bh >> 3, h = bh & 7;

    const int pi = w >> 1;            // pair index within block (0 or 1)
    const int c  = w & 1;             // chunk half
    const int p  = pi ? (j + 16) : j;
    const int qtA = p, qtB = 63 - p;
    const int ntA = (p >> 1) + 1;           // kv tiles for side A (<= 16)
    const int ntB = ((63 - p) >> 1) + 1;    // kv tiles for side B (ntA + ntB == 33)

    for (int i = tid; i < 4 * 32 * 66; i += 256) ((float*)Lacc)[i] = 0.f;
    if (tid < 128) ((float*)Ll)[tid] = 0.f;
    __syncthreads();

    const char* tb = (const char*)ws + (size_t)bh * NT_ * TILE_BYTES;

    // chunk split at linear tile 16: c=0 does A[0,ntA) + B[0,16-ntA)  (16 iters)
    //                                c=1 does B[16-ntA, ntB)          (17 iters)
    if (c == 0) {
        do_range(Q, tb, b0, h, qtA, 0, ntA, ntA - 1, lq, g, Lacc[pi * 2 + 0], Ll[pi * 2 + 0]);
        do_range(Q, tb, b0, h, qtB, 0, 16 - ntA, ntB - 1, lq, g, Lacc[pi * 2 + 1], Ll[pi * 2 + 1]);
    } else {
        do_range(Q, tb, b0, h, qtB, 16 - ntA, ntB, ntB - 1, lq, g, Lacc[pi * 2 + 1], Ll[pi * 2 + 1]);
    }

    __syncthreads();

    // combine epilogue: slot = pair*2+side; 256 threads cover 4 slots x 32 rows x 2 d-halves
    const int slot = tid >> 6;
    const int row  = (tid >> 1) & 31;
    const int d0   = (tid & 1) * 32;
    const int pE   = (slot >> 1) ? (j + 16) : j;
    const int qtE  = (slot & 1) ? (63 - pE) : pE;
    const float inv = 1.0f / Ll[slot][row];
    float* op = O + (((size_t)(b0 * L_ + qtE * 32 + row)) * H_ + h) * D_ + d0;
    #pragma unroll
    for (int i8 = 0; i8 < 8; ++i8) {
        f32x4 o;
        #pragma unroll
        for (int r = 0; r < 4; ++r) o[r] = Lacc[slot][row][d0 + i8 * 4 + r] * inv;
        *(f32x4*)(op + i8 * 4) = o;
    }
}

// ---------------- fallback (round-1 kernel, proven) for small ws ----------------
#define KPITCH 72
__global__ __launch_bounds__(256, 2) void attn_fwd_fb(
    const float* __restrict__ Q, const float* __restrict__ K,
    const float* __restrict__ V, float* __restrict__ O)
{
    __shared__ unsigned short Klds[64 * KPITCH];
    __shared__ unsigned short Vlds[64 * KPITCH];
    const int tid = threadIdx.x, lane = tid & 63, w = tid >> 6;
    const int lq = lane & 15, g = lane >> 4;
    const int bid = blockIdx.x, qb = bid & 31, bh = bid >> 5;
    const int b0 = bh >> 3, h = bh & 7;
    const int q0 = qb * 64, qrow = q0 + w * 16 + lq;
    const float* qptr = Q + ((size_t)(b0 * L_ + qrow) * H_ + h) * E_;
    bf16x8 qf[2];
    #pragma unroll
    for (int eb = 0; eb < 2; ++eb) {
        const float* pp = qptr + eb * 32 + g * 8;
        f32x4 a = *(const f32x4*)pp; f32x4 b = *(const f32x4*)(pp + 4);
        bf16x8 q;
        #pragma unroll
        for (int jq = 0; jq < 4; ++jq) { q[jq] = (short)f2bf(a[jq] * 0.125f); q[4 + jq] = (short)f2bf(b[jq] * 0.125f); }
        qf[eb] = q;
    }
    const int tr = tid >> 2, tc = tid & 3;
    const int rh = rho(tr);
    f32x4 acc[4] = {};
    float mrow = -INFINITY, lrow = 0.f;
    for (int kt = 0; kt < qb + 1; ++kt) {
        const int kv0 = kt * 64;
        __syncthreads();
        {
            const float* krow = K + ((size_t)((b0 * S_ + kv0 + tr)) * H_ + h) * E_;
            const float* vrow = V + ((size_t)((b0 * S_ + kv0 + tr)) * H_ + h) * D_;
            #pragma unroll
            for (int i = 0; i < 4; ++i) {
                const int e0 = tc * 4 + i * 16;
                f32x4 k4 = *(const f32x4*)(krow + e0);
                unsigned int lo = (unsigned)f2bf(k4[0]) | ((unsigned)f2bf(k4[1]) << 16);
                unsigned int hi = (unsigned)f2bf(k4[2]) | ((unsigned)f2bf(k4[3]) << 16);
                *(uint2*)&Klds[rh * KPITCH + e0] = make_uint2(lo, hi);
                f32x4 v4 = *(const f32x4*)(vrow + e0);
                #pragma unroll
                for (int k2 = 0; k2 < 4; ++k2) Vlds[(e0 + k2) * KPITCH + tr] = f2bf(v4[k2]);
            }
        }
        __syncthreads();
        f32x4 sc[4];
        #pragma unroll
        for (int st = 0; st < 4; ++st) {
            const unsigned short* kr = &Klds[(st * 16 + lq) * KPITCH];
            bf16x8 ka0 = *(const bf16x8*)(kr + 8 * g);
            bf16x8 ka1 = *(const bf16x8*)(kr + 32 + 8 * g);
            f32x4 cc = {0.f, 0.f, 0.f, 0.f};
            cc = __builtin_amdgcn_mfma_f32_16x16x32_bf16(ka0, qf[0], cc, 0, 0, 0);
            cc = __builtin_amdgcn_mfma_f32_16x16x32_bf16(ka1, qf[1], cc, 0, 0, 0);
            sc[st] = cc;
        }
        float tmax = -INFINITY;
        #pragma unroll
        for (int st = 0; st < 4; ++st) {
            const int kvb = kv0 + 32 * (st >> 1) + 8 * g + 4 * (st & 1);
            #pragma unroll
            for (int r = 0; r < 4; ++r) { if (kvb + r > qrow) sc[st][r] = -INFINITY; tmax = fmaxf(tmax, sc[st][r]); }
        }
        tmax = fmaxf(tmax, __shfl_xor(tmax, 16));
        tmax = fmaxf(tmax, __shfl_xor(tmax, 32));
        const float mnew = fmaxf(mrow, tmax);
        const float corr = __expf(mrow - mnew);
        float pv[4][4]; float tsum = 0.f;
        #pragma unroll
        for (int st = 0; st < 4; ++st)
            #pragma unroll
            for (int r = 0; r < 4; ++r) { float e = __expf(sc[st][r] - mnew); pv[st][r] = e; tsum += e; }
        tsum += __shfl_xor(tsum, 16); tsum += __shfl_xor(tsum, 32);
        lrow = lrow * corr + tsum; mrow = mnew;
        #pragma unroll
        for (int dt = 0; dt < 4; ++dt)
            #pragma unroll
            for (int r = 0; r < 4; ++r) acc[dt][r] *= corr;
        bf16x8 pb[2];
        #pragma unroll
        for (int bb = 0; bb < 2; ++bb)
            #pragma unroll
            for (int s = 0; s < 2; ++s)
                #pragma unroll
                for (int r = 0; r < 4; ++r) pb[bb][4 * s + r] = (short)f2bf(pv[2 * bb + s][r]);
        #pragma unroll
        for (int bb = 0; bb < 2; ++bb)
            #pragma unroll
            for (int dt = 0; dt < 4; ++dt) {
                bf16x8 va = *(const bf16x8*)&Vlds[(dt * 16 + lq) * KPITCH + 32 * bb + 8 * g];
                acc[dt] = __builtin_amdgcn_mfma_f32_16x16x32_bf16(va, pb[bb], acc[dt], 0, 0, 0);
            }
    }
    const float inv = 1.0f / lrow;
    float* optr = O + ((size_t)(b0 * L_ + qrow) * H_ + h) * D_;
    #pragma unroll
    for (int dt = 0; dt < 4; ++dt) {
        f32x4 o;
        #pragma unroll
        for (int r = 0; r < 4; ++r) o[r] = acc[dt][r] * inv;
        *(f32x4*)(optr + dt * 16 + 4 * g) = o;
    }
}

extern "C" void kernel_launch(void* const* d_in, const int* in_sizes, int n_in,
                              void* d_out, int out_size, void* d_ws, size_t ws_size,
                              hipStream_t stream) {
    const float* Q = (const float*)d_in[0];
    const float* K = (const float*)d_in[1];
    const float* V = (const float*)d_in[2];
    float* O = (float*)d_out;
    if (ws_size >= WS_NEEDED) {
        prep_kv<<<dim3(B_ * H_ * NT_), 256, 0, stream>>>(K, V, (unsigned short*)d_ws);
        attn7<<<dim3(512), 256, 0, stream>>>(Q, (const unsigned short*)d_ws, O);
    } else {
        attn_fwd_fb<<<dim3(B_ * H_ * 32), 256, 0, stream>>>(Q, K, V, O);
    }
}

// Round 8
// 49.080 us; speedup vs baseline: 1.3544x; 1.3544x over previous
//
#include <hip/hip_runtime.h>
#include <math.h>

typedef __attribute__((ext_vector_type(8))) short bf16x8;
typedef __attribute__((ext_vector_type(4))) float f32x4;
typedef __attribute__((ext_vector_type(4))) unsigned int u32x4;

#define B_ 4
#define L_ 2048
#define S_ 2048
#define H_ 8
#define E_ 64
#define D_ 64
#define NT_ 32                      // kv tiles of 64 per (b,h)
#define TILE_BYTES 16384            // 8KB K image + 8KB V^T image
#define WS_NEEDED ((size_t)B_ * H_ * NT_ * TILE_BYTES)
#define SCL (0.125f * 1.44269504088896f)   // 1/sqrt(E) * log2(e)

__device__ __forceinline__ unsigned short f2bf(float x) {
    unsigned int u = __builtin_bit_cast(unsigned int, x);
    u += 0x7fffu + ((u >> 16) & 1u);
    return (unsigned short)(u >> 16);
}
// kv-row permute so S^T C-fragment layout == PV A-operand layout (verified rounds 1-5)
__device__ __forceinline__ int rho(int r) {
    return (r & 32) | (((r >> 2) & 1) << 4) | (((r >> 3) & 3) << 2) | (r & 3);
}

// ---------------- prep: K -> bf16 tile image, V -> V^T image; XCD-aligned to consumer ----------------
// blockIdx encodes (kt, bh) such that bid%8 == bh%8: the tile is prepped (and L2-cached)
// on the same XCD whose attn blocks (bid%8==bh%8) will read it.
__global__ __launch_bounds__(256) void prep_kv(const float* __restrict__ K,
                                               const float* __restrict__ V,
                                               unsigned short* __restrict__ ws)
{
    __shared__ __align__(16) unsigned short vt[64][80];
    const int tid = threadIdx.x;
    const int bid = blockIdx.x;
    const int kt  = bid >> 5;                                 // 0..31
    const int bh  = (((bid >> 3) & 3) << 3) | (bid & 7);      // bid%8 == bh%8
    const int b   = bh >> 3, h = bh & 7;
    const int s0  = kt * 64;
    const int r   = tid >> 2;
    const int e0  = (tid & 3) * 16;

    const float* krow = K + (((size_t)(b * S_ + s0 + r)) * H_ + h) * E_ + e0;
    const float* vrow = V + (((size_t)(b * S_ + s0 + r)) * H_ + h) * D_ + e0;
    char* tile = (char*)(ws) + ((size_t)(bh * NT_ + kt) * TILE_BYTES);

    unsigned short kb[16];
    #pragma unroll
    for (int i = 0; i < 4; ++i) {
        f32x4 k4 = *(const f32x4*)(krow + i * 4);
        #pragma unroll
        for (int jq = 0; jq < 4; ++jq) kb[i * 4 + jq] = f2bf(k4[jq]);
    }
    {
        const int rr = rho(r);
        const int m  = (rr & 7) << 4;
        char* kbase = tile + rr * 128;
        u32x4 lo, hi;
        #pragma unroll
        for (int jq = 0; jq < 4; ++jq) {
            lo[jq] = (unsigned)kb[2 * jq] | ((unsigned)kb[2 * jq + 1] << 16);
            hi[jq] = (unsigned)kb[8 + 2 * jq] | ((unsigned)kb[9 + 2 * jq] << 16);
        }
        *(u32x4*)(kbase + ((2 * e0) ^ m))      = lo;
        *(u32x4*)(kbase + ((2 * e0 + 16) ^ m)) = hi;
    }
    #pragma unroll
    for (int i = 0; i < 4; ++i) {
        f32x4 v4 = *(const f32x4*)(vrow + i * 4);
        #pragma unroll
        for (int jq = 0; jq < 4; ++jq) vt[e0 + i * 4 + jq][r] = f2bf(v4[jq]);
    }
    __syncthreads();
    {
        const int d  = tid >> 2;
        const int c0 = (tid & 3) * 16;
        const int m  = (d & 7) << 4;
        char* vbase = tile + 8192 + d * 128;
        u32x4 lo = *(const u32x4*)&vt[d][c0];
        u32x4 hi = *(const u32x4*)&vt[d][c0 + 8];
        *(u32x4*)(vbase + ((2 * c0) ^ m))      = lo;
        *(u32x4*)(vbase + ((2 * c0 + 16) ^ m)) = hi;
    }
}

// ---------------- attention: uniform waves (full pair {p,63-p} = 33 iters each), no LDS/sync ----------------
#define GL16(dst, p, o) asm volatile("global_load_dwordx4 %0, %1, off offset:" o \
                                     : "=&v"(dst) : "v"(p) : "memory")

#define ISSUE_K() do { \
    GL16(ka[0], pKa, "-3072"); GL16(ka[1], pKb, "-3072"); \
    GL16(ka[2], pKa, "-1024"); GL16(ka[3], pKb, "-1024"); \
    GL16(ka[4], pKa, "1024");  GL16(ka[5], pKb, "1024");  \
    GL16(ka[6], pKa, "3072");  GL16(ka[7], pKb, "3072"); } while (0)

#define ISSUE_V() do { \
    GL16(vb[0], pVa, "-3072"); GL16(vb[1], pVb, "-3072"); \
    GL16(vb[2], pVa, "-1024"); GL16(vb[3], pVb, "-1024"); \
    GL16(vb[4], pVa, "1024");  GL16(vb[5], pVb, "1024");  \
    GL16(vb[6], pVa, "3072");  GL16(vb[7], pVb, "3072"); } while (0)

// full causal kv-range [0, nt) for 32-row q-tile qt; writes O directly (diag tile == nt-1)
__device__ __forceinline__ void do_tile(
    const float* __restrict__ Q, const char* __restrict__ tb,
    int b0, int h, int qt, int nt, int lq, int g, float* __restrict__ O)
{
    int qrow[2];
    qrow[0] = qt * 32 + lq;
    qrow[1] = qt * 32 + 16 + lq;

    // Q fragments (B-operand), scale*log2e folded => scores in exp2 domain
    bf16x8 qf[2][2];
    #pragma unroll
    for (int qs = 0; qs < 2; ++qs) {
        const float* qptr = Q + (((size_t)(b0 * L_ + qrow[qs])) * H_ + h) * E_;
        #pragma unroll
        for (int eb = 0; eb < 2; ++eb) {
            const float* pq = qptr + eb * 32 + g * 8;
            f32x4 a = *(const f32x4*)pq;
            f32x4 b = *(const f32x4*)(pq + 4);
            bf16x8 qv;
            #pragma unroll
            for (int k = 0; k < 4; ++k) {
                qv[k]     = (short)f2bf(a[k] * SCL);
                qv[4 + k] = (short)f2bf(b[k] * SCL);
            }
            qf[qs][eb] = qv;
        }
    }

    // per-lane pre-swizzled pointers (+3072 centers the ±3072 literal offsets)
    const int mm  = (lq & 7) << 4;
    const char* pKa = tb + lq * 128 + ((16 * g) ^ mm) + 3072;
    const char* pKb = tb + lq * 128 + ((64 + 16 * g) ^ mm) + 3072;
    const char* pVa = pKa + 8192;
    const char* pVb = pKb + 8192;

    u32x4 ka[8], vb[8];
    f32x4 acc[2][4] = {};
    float ls[2] = {0.f, 0.f};

    ISSUE_K();
    ISSUE_V();

    for (int kt = 0; kt < nt; ++kt) {
        // ---- wait K(kt) (V(kt) still in flight) ----
        asm volatile("s_waitcnt vmcnt(8)" ::: "memory");
        __builtin_amdgcn_sched_barrier(0);

        // ---- QK^T (swapped) from registers ----
        f32x4 sc[2][4];
        __builtin_amdgcn_s_setprio(1);
        #pragma unroll
        for (int st = 0; st < 4; ++st) {
            bf16x8 k0 = __builtin_bit_cast(bf16x8, ka[2 * st]);
            bf16x8 k1 = __builtin_bit_cast(bf16x8, ka[2 * st + 1]);
            #pragma unroll
            for (int qs = 0; qs < 2; ++qs) {
                f32x4 z = {0.f, 0.f, 0.f, 0.f};
                f32x4 cc = __builtin_amdgcn_mfma_f32_16x16x32_bf16(k0, qf[qs][0], z, 0, 0, 0);
                sc[qs][st] = __builtin_amdgcn_mfma_f32_16x16x32_bf16(k1, qf[qs][1], cc, 0, 0, 0);
            }
        }
        __builtin_amdgcn_s_setprio(0);

        const bool hasnext = (kt + 1 < nt);
        if (hasnext) { pKa += TILE_BYTES; pKb += TILE_BYTES; ISSUE_K(); }

        // ---- softmax (fixed base, exp2 domain) + pack P ----
        const int kv0 = kt * 64;
        u32x4 pw[2][2];
        #pragma unroll
        for (int qs = 0; qs < 2; ++qs) {
            #pragma unroll
            for (int st = 0; st < 4; ++st) {
                f32x4 cc = sc[qs][st];
                if (kt == nt - 1) {   // diagonal tile: causal mask
                    #pragma unroll
                    for (int r = 0; r < 4; ++r) {
                        const int kv = kv0 + 32 * (st >> 1) + 8 * g + 4 * (st & 1) + r;
                        if (kv > qrow[qs]) cc[r] = -INFINITY;
                    }
                }
                f32x4 ev;
                #pragma unroll
                for (int r = 0; r < 4; ++r)
                    asm("v_exp_f32 %0, %1" : "=v"(ev[r]) : "v"(cc[r]));
                ls[qs] += (ev[0] + ev[1]) + (ev[2] + ev[3]);
                asm("v_cvt_pk_bf16_f32 %0, %1, %2" : "=v"(pw[qs][st >> 1][2 * (st & 1)])     : "v"(ev[0]), "v"(ev[1]));
                asm("v_cvt_pk_bf16_f32 %0, %1, %2" : "=v"(pw[qs][st >> 1][2 * (st & 1) + 1]) : "v"(ev[2]), "v"(ev[3]));
            }
        }

        // ---- wait V(kt) ----
        if (hasnext) asm volatile("s_waitcnt vmcnt(8)" ::: "memory");
        else         asm volatile("s_waitcnt vmcnt(0)" ::: "memory");
        __builtin_amdgcn_sched_barrier(0);

        // ---- PV: O^T += V^T . P^T ----
        __builtin_amdgcn_s_setprio(1);
        #pragma unroll
        for (int dt = 0; dt < 4; ++dt) {
            bf16x8 v0 = __builtin_bit_cast(bf16x8, vb[2 * dt]);
            bf16x8 v1 = __builtin_bit_cast(bf16x8, vb[2 * dt + 1]);
            #pragma unroll
            for (int qs = 0; qs < 2; ++qs) {
                acc[qs][dt] = __builtin_amdgcn_mfma_f32_16x16x32_bf16(v0, __builtin_bit_cast(bf16x8, pw[qs][0]), acc[qs][dt], 0, 0, 0);
                acc[qs][dt] = __builtin_amdgcn_mfma_f32_16x16x32_bf16(v1, __builtin_bit_cast(bf16x8, pw[qs][1]), acc[qs][dt], 0, 0, 0);
            }
        }
        __builtin_amdgcn_s_setprio(0);

        if (hasnext) { pVa += TILE_BYTES; pVb += TILE_BYTES; ISSUE_V(); }
    }

    // ---- epilogue: reduce l across the 4 lane-groups, divide, store ----
    #pragma unroll
    for (int qs = 0; qs < 2; ++qs) {
        float l = ls[qs] + __shfl_xor(ls[qs], 16);
        l += __shfl_xor(l, 32);
        const float inv = 1.0f / l;
        float* op = O + (((size_t)(b0 * L_ + qrow[qs])) * H_ + h) * D_;
        #pragma unroll
        for (int dt = 0; dt < 4; ++dt) {
            f32x4 o;
            #pragma unroll
            for (int r = 0; r < 4; ++r) o[r] = acc[qs][dt][r] * inv;
            *(f32x4*)(op + dt * 16 + 4 * g) = o;
        }
    }
}

__global__ __launch_bounds__(128, 2) void attn8(const float* __restrict__ Q,
                                                const unsigned short* __restrict__ ws,
                                                float* __restrict__ O)
{
    const int tid  = threadIdx.x;
    const int lane = tid & 63;
    const int w    = tid >> 6;        // wave 0..1
    const int lq   = lane & 15;
    const int g    = lane >> 4;

    const int bid = blockIdx.x;
    const int bh  = bid & 31;         // attn block on XCD bh%8 == prep's XCD for this image
    const int jj  = bid >> 5;         // 0..15
    const int b0  = bh >> 3, h = bh & 7;

    // wave-job: full complementary pair {p, 63-p} -> exactly 33 kv-tile iterations per wave
    const int p   = jj * 2 + w;                 // 0..31
    const int ntA = (p >> 1) + 1;
    const int ntB = ((63 - p) >> 1) + 1;        // ntA + ntB == 33

    const char* tb = (const char*)ws + (size_t)bh * NT_ * TILE_BYTES;

    do_tile(Q, tb, b0, h, p,      ntA, lq, g, O);
    do_tile(Q, tb, b0, h, 63 - p, ntB, lq, g, O);
}

// ---------------- fallback (round-1 kernel, proven) for small ws ----------------
#define KPITCH 72
__global__ __launch_bounds__(256, 2) void attn_fwd_fb(
    const float* __restrict__ Q, const float* __restrict__ K,
    const float* __restrict__ V, float* __restrict__ O)
{
    __shared__ unsigned short Klds[64 * KPITCH];
    __shared__ unsigned short Vlds[64 * KPITCH];
    const int tid = threadIdx.x, lane = tid & 63, w = tid >> 6;
    const int lq = lane & 15, g = lane >> 4;
    const int bid = blockIdx.x, qb = bid & 31, bh = bid >> 5;
    const int b0 = bh >> 3, h = bh & 7;
    const int q0 = qb * 64, qrow = q0 + w * 16 + lq;
    const float* qptr = Q + ((size_t)(b0 * L_ + qrow) * H_ + h) * E_;
    bf16x8 qf[2];
    #pragma unroll
    for (int eb = 0; eb < 2; ++eb) {
        const float* pp = qptr + eb * 32 + g * 8;
        f32x4 a = *(const f32x4*)pp; f32x4 b = *(const f32x4*)(pp + 4);
        bf16x8 q;
        #pragma unroll
        for (int jq = 0; jq < 4; ++jq) { q[jq] = (short)f2bf(a[jq] * 0.125f); q[4 + jq] = (short)f2bf(b[jq] * 0.125f); }
        qf[eb] = q;
    }
    const int tr = tid >> 2, tc = tid & 3;
    const int rh = rho(tr);
    f32x4 acc[4] = {};
    float mrow = -INFINITY, lrow = 0.f;
    for (int kt = 0; kt < qb + 1; ++kt) {
        const int kv0 = kt * 64;
        __syncthreads();
        {
            const float* krow = K + ((size_t)((b0 * S_ + kv0 + tr)) * H_ + h) * E_;
            const float* vrow = V + ((size_t)((b0 * S_ + kv0 + tr)) * H_ + h) * D_;
            #pragma unroll
            for (int i = 0; i < 4; ++i) {
                const int e0 = tc * 4 + i * 16;
                f32x4 k4 = *(const f32x4*)(krow + e0);
                unsigned int lo = (unsigned)f2bf(k4[0]) | ((unsigned)f2bf(k4[1]) << 16);
                unsigned int hi = (unsigned)f2bf(k4[2]) | ((unsigned)f2bf(k4[3]) << 16);
                *(uint2*)&Klds[rh * KPITCH + e0] = make_uint2(lo, hi);
                f32x4 v4 = *(const f32x4*)(vrow + e0);
                #pragma unroll
                for (int k2 = 0; k2 < 4; ++k2) Vlds[(e0 + k2) * KPITCH + tr] = f2bf(v4[k2]);
            }
        }
        __syncthreads();
        f32x4 sc[4];
        #pragma unroll
        for (int st = 0; st < 4; ++st) {
            const unsigned short* kr = &Klds[(st * 16 + lq) * KPITCH];
            bf16x8 ka0 = *(const bf16x8*)(kr + 8 * g);
            bf16x8 ka1 = *(const bf16x8*)(kr + 32 + 8 * g);
            f32x4 cc = {0.f, 0.f, 0.f, 0.f};
            cc = __builtin_amdgcn_mfma_f32_16x16x32_bf16(ka0, qf[0], cc, 0, 0, 0);
            cc = __builtin_amdgcn_mfma_f32_16x16x32_bf16(ka1, qf[1], cc, 0, 0, 0);
            sc[st] = cc;
        }
        float tmax = -INFINITY;
        #pragma unroll
        for (int st = 0; st < 4; ++st) {
            const int kvb = kv0 + 32 * (st >> 1) + 8 * g + 4 * (st & 1);
            #pragma unroll
            for (int r = 0; r < 4; ++r) { if (kvb + r > qrow) sc[st][r] = -INFINITY; tmax = fmaxf(tmax, sc[st][r]); }
        }
        tmax = fmaxf(tmax, __shfl_xor(tmax, 16));
        tmax = fmaxf(tmax, __shfl_xor(tmax, 32));
        const float mnew = fmaxf(mrow, tmax);
        const float corr = __expf(mrow - mnew);
        float pv[4][4]; float tsum = 0.f;
        #pragma unroll
        for (int st = 0; st < 4; ++st)
            #pragma unroll
            for (int r = 0; r < 4; ++r) { float e = __expf(sc[st][r] - mnew); pv[st][r] = e; tsum += e; }
        tsum += __shfl_xor(tsum, 16); tsum += __shfl_xor(tsum, 32);
        lrow = lrow * corr + tsum; mrow = mnew;
        #pragma unroll
        for (int dt = 0; dt < 4; ++dt)
            #pragma unroll
            for (int r = 0; r < 4; ++r) acc[dt][r] *= corr;
        bf16x8 pb[2];
        #pragma unroll
        for (int bb = 0; bb < 2; ++bb)
            #pragma unroll
            for (int s = 0; s < 2; ++s)
                #pragma unroll
                for (int r = 0; r < 4; ++r) pb[bb][4 * s + r] = (short)f2bf(pv[2 * bb + s][r]);
        #pragma unroll
        for (int bb = 0; bb < 2; ++bb)
            #pragma unroll
            for (int dt = 0; dt < 4; ++dt) {
                bf16x8 va = *(const bf16x8*)&Vlds[(dt * 16 + lq) * KPITCH + 32 * bb + 8 * g];
                acc[dt] = __builtin_amdgcn_mfma_f32_16x16x32_bf16(va, pb[bb], acc[dt], 0, 0, 0);
            }
    }
    const float inv = 1.0f / lrow;
    float* optr = O + ((size_t)(b0 * L_ + qrow) * H_ + h) * D_;
    #pragma unroll
    for (int dt = 0; dt < 4; ++dt) {
        f32x4 o;
        #pragma unroll
        for (int r = 0; r < 4; ++r) o[r] = acc[dt][r] * inv;
        *(f32x4*)(optr + dt * 16 + 4 * g) = o;
    }
}

extern "C" void kernel_launch(void* const* d_in, const int* in_sizes, int n_in,
                              void* d_out, int out_size, void* d_ws, size_t ws_size,
                              hipStream_t stream) {
    const float* Q = (const float*)d_in[0];
    const float* K = (const float*)d_in[1];
    const float* V = (const float*)d_in[2];
    float* O = (float*)d_out;
    if (ws_size >= WS_NEEDED) {
        prep_kv<<<dim3(B_ * H_ * NT_), 256, 0, stream>>>(K, V, (unsigned short*)d_ws);
        attn8<<<dim3(512), 128, 0, stream>>>(Q, (const unsigned short*)d_ws, O);
    } else {
        attn_fwd_fb<<<dim3(B_ * H_ * 32), 256, 0, stream>>>(Q, K, V, O);
    }
}